// Round 7
// baseline (125.397 us; speedup 1.0000x reference)
//
#include <hip/hip_runtime.h>

#define B_ 2
#define N_ 512
#define C_ 128   // HIDDEN_DIM
#define A_ 64    // ATTN_DIM
#define H_ 128

#define SC2L 2.885390081777927f     // 2*log2(e): exp(2x)=2^(SC2L*x)
#define NEG2LE -2.885390081777927f  // -2*log2(e)

// workspace layout (float offsets)
#define OFF_WET 0                           // We^T [A][H]           (8192)
#define OFF_V   (OFF_WET + A_*H_)           // v = exp(2*h_o) [g][a] (65536)
#define OFF_US  (OFF_V  + B_*N_*A_)         // u = exp(2*h_1) [g][a] (65536)
#define OFF_XY  (OFF_US + B_*N_*A_)         // Xy [g][h]             (131072)
#define OFF_P   (OFF_XY + B_*N_*H_)         // p  [b][i][j]          (524288)
#define OFF_L   (OFF_P  + B_*N_*N_)         // l  [g]                (1024)

__device__ __forceinline__ float fexp2(float x) { return __builtin_amdgcn_exp2f(x); }
__device__ __forceinline__ float frcp(float x)  { return __builtin_amdgcn_rcpf(x); }

// ---------------- kernel 1: projections -> u, v, Xy, We^T ----------------
__global__ __launch_bounds__(512) void proj_kernel(
    const float* __restrict__ X, const float* __restrict__ Wo,
    const float* __restrict__ W1, const float* __restrict__ Wy,
    const float* __restrict__ by, const float* __restrict__ We,
    float* __restrict__ ws) {
  __shared__ float xs[2][C_];
  int row0 = blockIdx.x * 2;
  int t = threadIdx.x;
  if (t < 2*C_) xs[t >> 7][t & 127] = X[(size_t)row0*C_ + t];
  __syncthreads();

  int rsub = t >> 8;
  int col  = t & 255;
  int g = row0 + rsub;

  const float* W;
  if (col < 64)       W = Wo + (size_t)col*C_;
  else if (col < 128) W = W1 + (size_t)(col - 64)*C_;
  else                W = Wy + (size_t)(col - 128)*C_;

  const float4* w4 = (const float4*)W;
  const float4* x4 = (const float4*)xs[rsub];
  float acc = 0.f;
  #pragma unroll 8
  for (int k = 0; k < C_/4; ++k) {
    float4 wv = w4[k];
    float4 xv = x4[k];
    acc = fmaf(wv.x, xv.x, acc);
    acc = fmaf(wv.y, xv.y, acc);
    acc = fmaf(wv.z, xv.z, acc);
    acc = fmaf(wv.w, xv.w, acc);
  }

  if (col < 64) {
    ws[OFF_V + (size_t)g*A_ + col] = fexp2(SC2L * acc);
  } else if (col < 128) {
    ws[OFF_US + (size_t)g*A_ + (col - 64)] = fexp2(SC2L * acc);
  } else {
    ws[OFF_XY + (size_t)g*H_ + (col - 128)] = acc + by[col - 128];
  }

  if (blockIdx.x == 0) {   // transpose We [H][A] -> [A][H]
    for (int k = t; k < A_*H_; k += 512) {
      int h = k >> 6, a = k & 63;
      ws[OFF_WET + a*H_ + h] = We[k];
    }
  }
}

// ---------------- kernel 2: scores p[b,i,j] + row sums l ----------------
// 1024 blocks (one per row) x 512 threads (thread = j). 4 blocks/CU, 100% occ.
__global__ __launch_bounds__(512) void score_kernel(
    const float* __restrict__ Wphi, float* __restrict__ ws) {
  __shared__ __align__(16) float pkv[A_];
  __shared__ __align__(16) float pkw[A_];
  __shared__ float reds[8];

  int t = threadIdx.x;                 // j
  int bi = blockIdx.x;                 // 0..1023
  int b = bi >> 9, i = bi & (N_-1);
  int w = t >> 6, lane = t & 63;

  if (t < A_) {
    pkv[t] = ws[OFF_V + (size_t)(b*N_ + i)*A_ + t];
    pkw[t] = Wphi[t];
  }
  __syncthreads();

  const float4* u4 = (const float4*)(ws + OFF_US + (size_t)(b*N_)*A_)
                     + (size_t)t*(A_/4);
  const float4* pv = (const float4*)pkv;
  const float4* pw = (const float4*)pkw;

  float s = 0.f;
  #pragma unroll 4
  for (int a4 = 0; a4 < A_/4; ++a4) {
    float4 u  = u4[a4];
    float4 v  = pv[a4];
    float4 wq = pw[a4];
    s = fmaf(wq.x, frcp(fmaf(v.x, u.x, 1.f)), s);
    s = fmaf(wq.y, frcp(fmaf(v.y, u.y, 1.f)), s);
    s = fmaf(wq.z, frcp(fmaf(v.z, u.z, 1.f)), s);
    s = fmaf(wq.w, frcp(fmaf(v.w, u.w, 1.f)), s);
  }
  float p = fexp2(NEG2LE * s);         // shift-free softmax numerator, |2s| < 6
  ws[OFF_P + (size_t)bi*N_ + t] = p;

  float q = p;
  #pragma unroll
  for (int m = 1; m < 64; m <<= 1) q += __shfl_xor(q, m);
  if (lane == 0) reds[w] = q;
  __syncthreads();
  if (t == 0) {
    float l = 0.f;
    #pragma unroll
    for (int k = 0; k < 8; ++k) l += reds[k];
    ws[OFF_L + bi] = l;
  }
}

// ---------------- kernel 3: ebar + part1 + epilogue ----------------
// 512 blocks (row-pairs) x 512 threads. One barrier between compute & reduce.
__global__ __launch_bounds__(512) void out_kernel(
    const float* __restrict__ be, const float* __restrict__ ws,
    float* __restrict__ out) {
  __shared__ float pl[2][N_];          // the two p-rows            (4 KB)
  __shared__ float ebw[2][8][A_];      // ebar partials             (4 KB)
  __shared__ float p1s[2][4][H_];      // part1 partials            (4 KB)
  __shared__ float ebar[2][A_];
  __shared__ float lsh[2];

  int t = threadIdx.x;
  int blk = blockIdx.x;                // 0..511
  int b = blk >> 8;
  int i0 = (blk & 255) * 2;
  int g0 = b*N_ + i0;

  pl[0][t] = ws[OFF_P + (size_t)(g0)*N_ + t];
  pl[1][t] = ws[OFF_P + (size_t)(g0 + 1)*N_ + t];
  if (t < 2) lsh[t] = ws[OFF_L + g0 + t];
  __syncthreads();

  // ---- phase ebar: thread = (a = t&63, oct = t>>6); coalesced u reads
  {
    int a = t & 63, oct = t >> 6;
    float v0 = ws[OFF_V + (size_t)g0*A_ + a];
    float v1 = ws[OFF_V + (size_t)(g0 + 1)*A_ + a];
    const float* ub = ws + OFF_US + (size_t)(b*N_)*A_ + a;
    float c0 = 0.f, c1 = 0.f;
    #pragma unroll 4
    for (int jc = 0; jc < N_/8; ++jc) {
      int j = oct*(N_/8) + jc;
      float u = ub[(size_t)j*A_];
      float p0 = pl[0][j], p1 = pl[1][j];
      c0 = fmaf(p0, frcp(fmaf(v0, u, 1.f)), c0);
      c1 = fmaf(p1, frcp(fmaf(v1, u, 1.f)), c1);
    }
    ebw[0][oct][a] = c0;
    ebw[1][oct][a] = c1;
  }

  // ---- phase part1: thread = (h = t&127, qd = t>>7); coalesced Xy reads
  {
    int h = t & 127, qd = t >> 7;
    const float* xq = ws + OFF_XY + (size_t)(b*N_ + qd*128)*H_ + h;
    float d0 = 0.f, d1 = 0.f;
    #pragma unroll 4
    for (int jc = 0; jc < 128; ++jc) {
      int j = qd*128 + jc;
      float xv = xq[(size_t)jc*H_];
      d0 = fmaf(pl[0][j], xv, d0);
      d1 = fmaf(pl[1][j], xv, d1);
    }
    p1s[0][qd][h] = d0;
    p1s[1][qd][h] = d1;
  }
  __syncthreads();

  // ---- reduce ebar: ebar_un[r][a] = l_r - 2*sum_oct
  if (t < 2*A_) {
    int r = t >> 6, a = t & 63;
    float e = 0.f;
    #pragma unroll
    for (int k = 0; k < 8; ++k) e += ebw[r][k][a];
    ebar[r][a] = lsh[r] - 2.0f*e;
  }
  __syncthreads();

  // ---- epilogue: out = (part1_un + We^T·ebar_un)/l + be
  if (t < 2*H_) {
    int r = t >> 7, h = t & 127;
    float acc = p1s[r][0][h] + p1s[r][1][h] + p1s[r][2][h] + p1s[r][3][h];
    float e2 = 0.f;
    const float* wet = ws + OFF_WET;
    #pragma unroll 8
    for (int a = 0; a < A_; ++a) e2 = fmaf(ebar[r][a], wet[a*H_ + h], e2);
    out[(size_t)(g0 + r)*H_ + h] = (acc + e2) * frcp(lsh[r]) + be[h];
  }
}

extern "C" void kernel_launch(void* const* d_in, const int* in_sizes, int n_in,
                              void* d_out, int out_size, void* d_ws, size_t ws_size,
                              hipStream_t stream) {
  const float* X    = (const float*)d_in[0];
  const float* Wo   = (const float*)d_in[1];
  const float* W1   = (const float*)d_in[2];
  const float* Wphi = (const float*)d_in[3];
  const float* Wy   = (const float*)d_in[4];
  const float* by   = (const float*)d_in[5];
  const float* We   = (const float*)d_in[6];
  const float* be   = (const float*)d_in[7];
  float* out = (float*)d_out;
  float* ws  = (float*)d_ws;

  hipLaunchKernelGGL(proj_kernel, dim3(B_*N_/2), dim3(512), 0, stream,
                     X, Wo, W1, Wy, by, We, ws);
  hipLaunchKernelGGL(score_kernel, dim3(B_*N_), dim3(512), 0, stream,
                     Wphi, ws);
  hipLaunchKernelGGL(out_kernel, dim3(B_*N_/2), dim3(512), 0, stream,
                     be, ws, out);
}

// Round 8
// 99.503 us; speedup vs baseline: 1.2602x; 1.2602x over previous
//
#include <hip/hip_runtime.h>

#define B_ 2
#define N_ 512
#define C_ 128   // HIDDEN_DIM
#define A_ 64    // ATTN_DIM
#define H_ 128

#define SC2L 2.885390081777927f   // 2*log2(e)
#define LG2E 1.4426950408889634f  // log2(e)

// workspace layout (float offsets)
#define OFF_WOT 0
#define OFF_W1T (OFF_WOT + C_*A_)           // transposed Wo [C][A]
#define OFF_WYT (OFF_W1T + C_*A_)           // transposed W1 [C][A]
#define OFF_WET (OFF_WYT + C_*H_)           // transposed Wy [C][H]
#define OFF_TO  (OFF_WET + A_*H_)           // tanh(h_o) [g][a]
#define OFF_T1S (OFF_TO + B_*N_*A_)         // tanh(h_1) [g][a]
#define OFF_T1T (OFF_T1S + B_*N_*A_)        // tanh(h_1) [b][a][n]
#define OFF_XY  (OFF_T1T + B_*N_*A_)        // Xy [g][h]

__device__ __forceinline__ float fexp2(float x) { return __builtin_amdgcn_exp2f(x); }
__device__ __forceinline__ float frcp(float x)  { return __builtin_amdgcn_rcpf(x); }
__device__ __forceinline__ float ftanh(float x) {
  return 1.0f - 2.0f * frcp(fexp2(SC2L * x) + 1.0f);
}

// ---------------- kernel 0: transpose weights into ws ----------------
__global__ __launch_bounds__(256) void prep_weights(
    const float* __restrict__ Wo, const float* __restrict__ W1,
    const float* __restrict__ Wy, const float* __restrict__ We,
    float* __restrict__ ws) {
  int t = blockIdx.x * 256 + threadIdx.x;   // 0..16383
  if (t < A_*C_) {                          // Wo,W1 [A][C] -> [C][A]; We [H][A] -> [A][H]
    int a = t / C_, c = t % C_;
    ws[OFF_WOT + c*A_ + a] = Wo[t];
    ws[OFF_W1T + c*A_ + a] = W1[t];
    int h2 = t / A_, a2 = t % A_;
    ws[OFF_WET + a2*H_ + h2] = We[t];
  }
  if (t < H_*C_) {                          // Wy [H][C] -> [C][H]
    int h = t / C_, c = t % C_;
    ws[OFF_WYT + c*H_ + h] = Wy[t];
  }
}

// ---------------- kernel 1: projections + tanh (coalesced transposed W) ----
// 2 rows per block (512 blocks); thread t computes one output column.
__global__ __launch_bounds__(256) void proj_kernel(
    const float* __restrict__ X, const float* __restrict__ by,
    float* __restrict__ ws) {
  __shared__ float xs[2*C_];
  int row0 = blockIdx.x * 2;
  int t = threadIdx.x;
  if (t < 2*C_) xs[t] = X[(size_t)row0*C_ + t];
  __syncthreads();

  const float* wt;
  int col, stride;
  if (t < 64)       { wt = ws + OFF_WOT; col = t;       stride = A_; }
  else if (t < 128) { wt = ws + OFF_W1T; col = t - 64;  stride = A_; }
  else              { wt = ws + OFF_WYT; col = t - 128; stride = H_; }

  float acc0 = 0.f, acc1 = 0.f;
  #pragma unroll 8
  for (int c = 0; c < C_; ++c) {
    float wv = wt[c*stride + col];
    acc0 = fmaf(xs[c], wv, acc0);
    acc1 = fmaf(xs[C_ + c], wv, acc1);
  }
  if (t < 64) {
    float* o = ws + OFF_TO + (size_t)row0*A_ + col;
    o[0] = ftanh(acc0); o[A_] = ftanh(acc1);
  } else if (t < 128) {
    float t0 = ftanh(acc0), t1 = ftanh(acc1);
    float* o = ws + OFF_T1S + (size_t)row0*A_ + col;
    o[0] = t0; o[A_] = t1;
    int b = row0 >> 9, n0 = row0 & (N_-1);
    float* oT = ws + OFF_T1T + (size_t)b*A_*N_ + (size_t)col*N_ + n0;
    oT[0] = t0; oT[1] = t1;
  } else {
    float bb = by[col];
    float* o = ws + OFF_XY + (size_t)row0*H_ + col;
    o[0] = acc0 + bb; o[H_] = acc1 + bb;
  }
}

// ---------------- kernel 2: attention, TI=1 ----------------
// 1024 blocks (one per query row) x 512 threads = 4 blocks/CU, 32 waves/CU.
// tanh(to + h1) = (to + tb) * rcp(1 + to*tb); shift-free softmax (|s| < 2.6).
__global__ __launch_bounds__(512) void attn_kernel(
    const float* __restrict__ Wphi, const float* __restrict__ be,
    const float* __restrict__ ws, float* __restrict__ out) {
  __shared__ __align__(16) float4 pk[A_];   // {to, wv*to, wv, 0}
  __shared__ float tos[A_];                 // to (stride-1 for Pass C)
  __shared__ float sc[N_];                  // p_j
  __shared__ float reds[8];
  __shared__ float ebw[8][A_];
  __shared__ float ebar[A_];
  __shared__ float p1s[4][H_];

  int t = threadIdx.x;
  int w = t >> 6, lane = t & 63;
  int bi = blockIdx.x;                      // 0..1023 = global row
  int b = bi >> 9, i = bi & (N_-1);

  const float* t1s = ws + OFF_T1S + (size_t)(b*N_)*A_;
  const float* t1t = ws + OFF_T1T + (size_t)b*A_*N_;
  const float* xyg = ws + OFF_XY  + (size_t)(b*N_)*H_;
  const float* wet = ws + OFF_WET;

  if (t < A_) {
    float to = ws[OFF_TO + (size_t)(b*N_ + i)*A_ + t];
    float wv = Wphi[t];
    pk[t] = make_float4(to, wv*to, wv, 0.f);
    tos[t] = to;
  }
  __syncthreads();

  // ---- Pass A: thread owns j = t; coalesced t1t reads
  float s = 0.f;
  {
    const float* t1p = t1t + t;
    #pragma unroll 8
    for (int a = 0; a < A_; ++a) {
      float tb = t1p[(size_t)a*N_];
      float4 k = pk[a];
      float den = fmaf(k.x, tb, 1.0f);      // 1 + to*tb
      float num = fmaf(k.z, tb, k.y);       // wv*tb + wv*to
      s = fmaf(num, frcp(den), s);
    }
  }
  float p = fexp2(LG2E * s);                // no max-shift: |s| <= ~2.6
  sc[t] = p;
  float q = p;
  #pragma unroll
  for (int m = 1; m < 64; m <<= 1) q += __shfl_xor(q, m);
  if (lane == 0) reds[w] = q;
  __syncthreads();

  // ---- Pass C: lane = a; wave w covers j = jj*8 + w; coalesced t1s reads
  {
    float to = tos[lane];
    float c = 0.f;
    #pragma unroll 8
    for (int jj = 0; jj < N_/8; ++jj) {
      int j = jj*8 + w;
      float tb = t1s[(size_t)j*A_ + lane];
      float pj = sc[j];
      float den = fmaf(to, tb, 1.0f);
      c = fmaf(pj*(to + tb), frcp(den), c);
    }
    ebw[w][lane] = c;
  }

  // ---- part1: thread = (qd = t>>7, h = t&127); coalesced Xy reads
  {
    int h = t & 127, qd = t >> 7;
    const float* xq = xyg + (size_t)(qd*128)*H_ + h;
    float d = 0.f;
    #pragma unroll 8
    for (int jc = 0; jc < 128; ++jc) {
      d = fmaf(sc[qd*128 + jc], xq[(size_t)jc*H_], d);
    }
    p1s[qd][h] = d;
  }
  __syncthreads();

  // ---- reduce ebar
  if (t < A_) {
    float e = 0.f;
    #pragma unroll
    for (int k = 0; k < 8; ++k) e += ebw[k][t];
    ebar[t] = e;
  }
  __syncthreads();

  // ---- epilogue: out = (part1_un + We^T·ebar_un)/l + be
  if (t < H_) {
    int h = t;
    float l = 0.f;
    #pragma unroll
    for (int k = 0; k < 8; ++k) l += reds[k];
    float acc = p1s[0][h] + p1s[1][h] + p1s[2][h] + p1s[3][h];
    float e2 = 0.f;
    #pragma unroll 8
    for (int a = 0; a < A_; ++a) e2 = fmaf(ebar[a], wet[a*H_ + h], e2);
    out[(size_t)bi*H_ + h] = (acc + e2) * frcp(l) + be[h];
  }
}

extern "C" void kernel_launch(void* const* d_in, const int* in_sizes, int n_in,
                              void* d_out, int out_size, void* d_ws, size_t ws_size,
                              hipStream_t stream) {
  const float* X    = (const float*)d_in[0];
  const float* Wo   = (const float*)d_in[1];
  const float* W1   = (const float*)d_in[2];
  const float* Wphi = (const float*)d_in[3];
  const float* Wy   = (const float*)d_in[4];
  const float* by   = (const float*)d_in[5];
  const float* We   = (const float*)d_in[6];
  const float* be   = (const float*)d_in[7];
  float* out = (float*)d_out;
  float* ws  = (float*)d_ws;

  hipLaunchKernelGGL(prep_weights, dim3(64), dim3(256), 0, stream, Wo, W1, Wy, We, ws);
  hipLaunchKernelGGL(proj_kernel, dim3(B_*N_/2), dim3(256), 0, stream, X, by, ws);
  hipLaunchKernelGGL(attn_kernel, dim3(B_*N_), dim3(512), 0, stream, Wphi, be, ws, out);
}

// Round 9
// 94.557 us; speedup vs baseline: 1.3261x; 1.0523x over previous
//
#include <hip/hip_runtime.h>

#define B_ 2
#define N_ 512
#define C_ 128   // HIDDEN_DIM
#define A_ 64    // ATTN_DIM
#define H_ 128

#define SC2L 2.885390081777927f     // 2*log2(e): exp(2x) = 2^(SC2L*x)
#define NEG2LE -2.885390081777927f  // -2*log2(e)

// workspace layout (float offsets)
#define OFF_WOT 0                           // Wo^T [C][A]  (8192)
#define OFF_W1T (OFF_WOT + C_*A_)           // W1^T [C][A]  (8192)
#define OFF_WYT (OFF_W1T + C_*A_)           // Wy^T [C][H]  (16384)
#define OFF_WET (OFF_WYT + C_*H_)           // We^T [A][H]  (8192)
#define OFF_V   (OFF_WET + A_*H_)           // v = exp(2 h_o) fp32 [g][a] (65536)
#define OFF_UT2 (OFF_V   + B_*N_*A_)        // u bf16 pairs [b][a/2][n] as uint (32768)
#define OFF_USP (OFF_UT2 + B_*N_*A_/2)      // u bf16 pairs [b][j/2][a] as uint (32768)
#define OFF_XYP (OFF_USP + B_*N_*A_/2)      // Xy bf16 pairs [b][j/2][h] as uint (65536)

__device__ __forceinline__ float fexp2(float x) { return __builtin_amdgcn_exp2f(x); }
__device__ __forceinline__ float frcp(float x)  { return __builtin_amdgcn_rcpf(x); }
__device__ __forceinline__ unsigned f2bf(float x) {   // fp32 -> bf16 bits (RNE)
  unsigned u = __float_as_uint(x);
  return (u + 0x7fffu + ((u >> 16) & 1u)) >> 16;
}
__device__ __forceinline__ float bf_lo(unsigned d) { return __uint_as_float(d << 16); }
__device__ __forceinline__ float bf_hi(unsigned d) { return __uint_as_float(d & 0xffff0000u); }

// ---------------- kernel 0: transpose weights into ws ----------------
__global__ __launch_bounds__(256) void prep_weights(
    const float* __restrict__ Wo, const float* __restrict__ W1,
    const float* __restrict__ Wy, const float* __restrict__ We,
    float* __restrict__ ws) {
  int t = blockIdx.x * 256 + threadIdx.x;   // 0..16383
  if (t < A_*C_) {
    int a = t / C_, c = t % C_;
    ws[OFF_WOT + c*A_ + a] = Wo[t];
    ws[OFF_W1T + c*A_ + a] = W1[t];
    int h2 = t / A_, a2 = t % A_;
    ws[OFF_WET + a2*H_ + h2] = We[t];
  }
  if (t < H_*C_) {
    int h = t / C_, c = t % C_;
    ws[OFF_WYT + c*H_ + h] = Wy[t];
  }
}

// ---------------- kernel 1: projections -> v (fp32), u & Xy (bf16 pairs) ---
// 512 blocks x 256 threads, 2 rows/block (one j-pair / row-pair per block).
__global__ __launch_bounds__(256) void proj_kernel(
    const float* __restrict__ X, const float* __restrict__ by,
    float* __restrict__ ws) {
  __shared__ float xs[2*C_];
  int row0 = blockIdx.x * 2;            // even; both rows in same batch
  int t = threadIdx.x;
  if (t < 2*C_) xs[t] = X[(size_t)row0*C_ + t];
  __syncthreads();

  const float* wt;
  int col, stride;
  if (t < 64)       { wt = ws + OFF_WOT; col = t;       stride = A_; }
  else if (t < 128) { wt = ws + OFF_W1T; col = t - 64;  stride = A_; }
  else              { wt = ws + OFF_WYT; col = t - 128; stride = H_; }

  float acc0 = 0.f, acc1 = 0.f;
  #pragma unroll 8
  for (int c = 0; c < C_; ++c) {
    float wv = wt[c*stride + col];
    acc0 = fmaf(xs[c], wv, acc0);
    acc1 = fmaf(xs[C_ + c], wv, acc1);
  }

  int b = row0 >> 9, n0 = row0 & (N_-1);
  int k = n0 >> 1;                      // j-pair index within batch

  if (t < 64) {                         // v = exp(2 h_o), fp32
    float* o = ws + OFF_V + (size_t)row0*A_ + col;
    o[0] = fexp2(SC2L * acc0);
    o[A_] = fexp2(SC2L * acc1);
  } else if (t < 128) {                 // u = exp(2 h_1), bf16
    int a = col;
    unsigned u0 = f2bf(fexp2(SC2L * acc0));
    unsigned u1 = f2bf(fexp2(SC2L * acc1));
    // uSP [b][k][a]: pack(j=2k, j=2k+1)
    unsigned* usp = (unsigned*)(ws + OFF_USP);
    usp[(size_t)(b*(N_/2) + k)*A_ + a] = u0 | (u1 << 16);
    // uT2 [b][a>>1][n], halves by a&1
    unsigned short* ut = (unsigned short*)(ws + OFF_UT2);
    size_t base = ((size_t)(b*(A_/2) + (a >> 1))*N_ + n0)*2 + (a & 1);
    ut[base] = (unsigned short)u0;
    ut[base + 2] = (unsigned short)u1;
  } else {                              // Xy bf16 pairs [b][k][h]
    int h = col;
    float bb = by[h];
    unsigned x0 = f2bf(acc0 + bb);
    unsigned x1 = f2bf(acc1 + bb);
    unsigned* xp = (unsigned*)(ws + OFF_XYP);
    xp[(size_t)(b*(N_/2) + k)*H_ + h] = x0 | (x1 << 16);
  }
}

// ---------------- kernel 2: attention, TI=1, bf16 packed streams ----------
// 1024 blocks x 512 threads = 4 blocks/CU, 32 waves/CU.
__global__ __launch_bounds__(512) void attn_kernel(
    const float* __restrict__ Wphi, const float* __restrict__ be,
    const float* __restrict__ ws, float* __restrict__ out) {
  __shared__ __align__(16) float2 pk2[A_];  // {v_a, wphi_a}
  __shared__ float sc[N_];                  // p_j
  __shared__ float reds[8];
  __shared__ float ebw[8][A_];
  __shared__ float ebar[A_];
  __shared__ float p1s[4][H_];

  int t = threadIdx.x;
  int w = t >> 6, lane = t & 63;
  int bi = blockIdx.x;                      // global row
  int b = bi >> 9, i = bi & (N_-1);

  const unsigned* ut2 = (const unsigned*)(ws + OFF_UT2) + (size_t)b*(A_/2)*N_;
  const unsigned* usp = (const unsigned*)(ws + OFF_USP) + (size_t)b*(N_/2)*A_;
  const unsigned* xyp = (const unsigned*)(ws + OFF_XYP) + (size_t)b*(N_/2)*H_;
  const float* wet = ws + OFF_WET;

  if (t < A_) {
    pk2[t] = make_float2(ws[OFF_V + (size_t)(b*N_ + i)*A_ + t], Wphi[t]);
  }
  __syncthreads();

  // ---- Pass A: thread owns j = t.  s' = sum_a wphi_a * rcp(v_a*u_ja + 1)
  float s = 0.f;
  {
    const unsigned* up = ut2 + t;           // stride N_ per a-pair
    const float4* pkq = (const float4*)pk2; // {v0,w0,v1,w1} per a-pair
    #pragma unroll 8
    for (int a2 = 0; a2 < A_/2; ++a2) {
      unsigned d = up[(size_t)a2*N_];
      float u0 = bf_lo(d), u1 = bf_hi(d);
      float4 vw = pkq[a2];
      s = fmaf(vw.y, frcp(fmaf(vw.x, u0, 1.f)), s);
      s = fmaf(vw.w, frcp(fmaf(vw.z, u1, 1.f)), s);
    }
  }
  float p = fexp2(NEG2LE * s);              // shift-free softmax numerator
  sc[t] = p;
  float q = p;
  #pragma unroll
  for (int m = 1; m < 64; m <<= 1) q += __shfl_xor(q, m);
  if (lane == 0) reds[w] = q;
  __syncthreads();

  // ---- Pass C: lane = a; wave w covers j-pairs k = kk*8 + w
  {
    float v = pk2[lane].x;
    const unsigned* up = usp + lane;
    float c = 0.f;
    #pragma unroll 8
    for (int kk = 0; kk < N_/16; ++kk) {
      int k = kk*8 + w;
      unsigned d = up[(size_t)k*A_];
      float u0 = bf_lo(d), u1 = bf_hi(d);
      float p0 = sc[2*k], p1 = sc[2*k + 1];
      c = fmaf(p0, frcp(fmaf(v, u0, 1.f)), c);
      c = fmaf(p1, frcp(fmaf(v, u1, 1.f)), c);
    }
    ebw[w][lane] = c;
  }

  // ---- part1: thread = (qd = t>>7, h = t&127); j-pairs k in [qd*64, qd*64+64)
  {
    int h = t & 127, qd = t >> 7;
    const unsigned* xp = xyp + (size_t)(qd*64)*H_ + h;
    float d0 = 0.f;
    #pragma unroll 8
    for (int kc = 0; kc < 64; ++kc) {
      unsigned d = xp[(size_t)kc*H_];
      int j = (qd*64 + kc)*2;
      d0 = fmaf(sc[j],     bf_lo(d), d0);
      d0 = fmaf(sc[j + 1], bf_hi(d), d0);
    }
    p1s[qd][h] = d0;
  }
  __syncthreads();

  // ---- reduce ebar: ebar_un[a] = l - 2*sum_w ebw[w][a]
  if (t < A_) {
    float e = 0.f;
    #pragma unroll
    for (int k = 0; k < 8; ++k) e += ebw[k][t];
    float l = 0.f;
    #pragma unroll
    for (int k = 0; k < 8; ++k) l += reds[k];
    ebar[t] = l - 2.0f*e;
  }
  __syncthreads();

  // ---- epilogue: out = (part1_un + We^T·ebar_un)/l + be
  if (t < H_) {
    int h = t;
    float l = 0.f;
    #pragma unroll
    for (int k = 0; k < 8; ++k) l += reds[k];
    float acc = p1s[0][h] + p1s[1][h] + p1s[2][h] + p1s[3][h];
    float e2 = 0.f;
    #pragma unroll 8
    for (int a = 0; a < A_; ++a) e2 = fmaf(ebar[a], wet[a*H_ + h], e2);
    out[(size_t)bi*H_ + h] = (acc + e2) * frcp(l) + be[h];
  }
}

extern "C" void kernel_launch(void* const* d_in, const int* in_sizes, int n_in,
                              void* d_out, int out_size, void* d_ws, size_t ws_size,
                              hipStream_t stream) {
  const float* X    = (const float*)d_in[0];
  const float* Wo   = (const float*)d_in[1];
  const float* W1   = (const float*)d_in[2];
  const float* Wphi = (const float*)d_in[3];
  const float* Wy   = (const float*)d_in[4];
  const float* by   = (const float*)d_in[5];
  const float* We   = (const float*)d_in[6];
  const float* be   = (const float*)d_in[7];
  float* out = (float*)d_out;
  float* ws  = (float*)d_ws;

  hipLaunchKernelGGL(prep_weights, dim3(64), dim3(256), 0, stream, Wo, W1, Wy, We, ws);
  hipLaunchKernelGGL(proj_kernel, dim3(B_*N_/2), dim3(256), 0, stream, X, by, ws);
  hipLaunchKernelGGL(attn_kernel, dim3(B_*N_), dim3(512), 0, stream, Wphi, be, ws, out);
}

// Round 10
// 92.477 us; speedup vs baseline: 1.3560x; 1.0225x over previous
//
#include <hip/hip_runtime.h>

#define B_ 2
#define N_ 512
#define C_ 128   // HIDDEN_DIM
#define A_ 64    // ATTN_DIM
#define H_ 128

#define SC2L 2.885390081777927f     // 2*log2(e): exp(2x) = 2^(SC2L*x)
#define NEG2LE -2.885390081777927f  // -2*log2(e)

// workspace layout (float offsets)
#define OFF_WOT 0                           // Wo^T [C][A]
#define OFF_W1T (OFF_WOT + C_*A_)           // W1^T [C][A]
#define OFF_WYT (OFF_W1T + C_*A_)           // Wy^T [C][H]
#define OFF_WET (OFF_WYT + C_*H_)           // We^T [A][H]
#define OFF_V   (OFF_WET + A_*H_)           // v = exp(2 h_o) fp32 [g][a]
#define OFF_UT8 (OFF_V   + B_*N_*A_)        // u bf16 [b][a/8][n][8]  (32768 fl)
#define OFF_US8 (OFF_UT8 + B_*N_*A_/2)      // u bf16 [b][j/8][a][8]  (32768 fl)
#define OFF_XYP (OFF_US8 + B_*N_*A_/2)      // Xy bf16 pairs [b][j/2][h] (65536 fl)

__device__ __forceinline__ float fexp2(float x) { return __builtin_amdgcn_exp2f(x); }
__device__ __forceinline__ float frcp(float x)  { return __builtin_amdgcn_rcpf(x); }
__device__ __forceinline__ unsigned f2bf(float x) {   // fp32 -> bf16 bits (RNE)
  unsigned u = __float_as_uint(x);
  return (u + 0x7fffu + ((u >> 16) & 1u)) >> 16;
}
__device__ __forceinline__ float bf_lo(unsigned d) { return __uint_as_float(d << 16); }
__device__ __forceinline__ float bf_hi(unsigned d) { return __uint_as_float(d & 0xffff0000u); }

// ---------------- kernel 0: transpose weights into ws ----------------
__global__ __launch_bounds__(256) void prep_weights(
    const float* __restrict__ Wo, const float* __restrict__ W1,
    const float* __restrict__ Wy, const float* __restrict__ We,
    float* __restrict__ ws) {
  int t = blockIdx.x * 256 + threadIdx.x;   // 0..16383
  if (t < A_*C_) {
    int a = t / C_, c = t % C_;
    ws[OFF_WOT + c*A_ + a] = Wo[t];
    ws[OFF_W1T + c*A_ + a] = W1[t];
    int h2 = t / A_, a2 = t % A_;
    ws[OFF_WET + a2*H_ + h2] = We[t];
  }
  if (t < H_*C_) {
    int h = t / C_, c = t % C_;
    ws[OFF_WYT + c*H_ + h] = Wy[t];
  }
}

// ---------------- kernel 1: projections -> v (fp32), u & Xy (bf16) --------
// 512 blocks x 256 threads, 2 rows/block (one j-pair, same batch).
__global__ __launch_bounds__(256) void proj_kernel(
    const float* __restrict__ X, const float* __restrict__ by,
    float* __restrict__ ws) {
  __shared__ float xs[2*C_];
  int row0 = blockIdx.x * 2;            // even
  int t = threadIdx.x;
  if (t < 2*C_) xs[t] = X[(size_t)row0*C_ + t];
  __syncthreads();

  const float* wt;
  int col, stride;
  if (t < 64)       { wt = ws + OFF_WOT; col = t;       stride = A_; }
  else if (t < 128) { wt = ws + OFF_W1T; col = t - 64;  stride = A_; }
  else              { wt = ws + OFF_WYT; col = t - 128; stride = H_; }

  float acc0 = 0.f, acc1 = 0.f;
  #pragma unroll 8
  for (int c = 0; c < C_; ++c) {
    float wv = wt[c*stride + col];
    acc0 = fmaf(xs[c], wv, acc0);
    acc1 = fmaf(xs[C_ + c], wv, acc1);
  }

  int b = row0 >> 9, n0 = row0 & (N_-1);

  if (t < 64) {                         // v = exp(2 h_o), fp32
    float* o = ws + OFF_V + (size_t)row0*A_ + col;
    o[0] = fexp2(SC2L * acc0);
    o[A_] = fexp2(SC2L * acc1);
  } else if (t < 128) {                 // u = exp(2 h_1), bf16, two layouts
    int a = col;
    unsigned u0 = f2bf(fexp2(SC2L * acc0));
    unsigned u1 = f2bf(fexp2(SC2L * acc1));
    // ut8 [b][a>>3][n][a&7]
    unsigned short* ut = (unsigned short*)(ws + OFF_UT8);
    size_t bA = ((size_t)(b*8 + (a >> 3))*N_ + n0)*8 + (a & 7);
    ut[bA] = (unsigned short)u0;
    ut[bA + 8] = (unsigned short)u1;
    // us8 [b][j>>3][a][j&7]  (n0 even -> same octet)
    unsigned short* us = (unsigned short*)(ws + OFF_US8);
    size_t bC = ((size_t)(b*64 + (n0 >> 3))*A_ + a)*8 + (n0 & 7);
    us[bC] = (unsigned short)u0;
    us[bC + 1] = (unsigned short)u1;
  } else {                              // Xy bf16 pairs [b][k][h]
    int h = col;
    float bb = by[h];
    unsigned x0 = f2bf(acc0 + bb);
    unsigned x1 = f2bf(acc1 + bb);
    unsigned* xp = (unsigned*)(ws + OFF_XYP);
    xp[(size_t)(b*(N_/2) + (n0 >> 1))*H_ + h] = x0 | (x1 << 16);
  }
}

// ---------------- kernel 2: attention, TI=1, dwordx4 bf16 streams ---------
// 1024 blocks x 512 threads = 4 blocks/CU target, 32 waves/CU.
__global__ __launch_bounds__(512) void attn_kernel(
    const float* __restrict__ Wphi, const float* __restrict__ be,
    const float* __restrict__ ws, float* __restrict__ out) {
  __shared__ __align__(16) float pkv[A_];   // v_a
  __shared__ __align__(16) float pkw[A_];   // wphi_a
  __shared__ float sc[N_];                  // p_j
  __shared__ float reds[8];
  __shared__ float ebw[8][A_];
  __shared__ float ebar[A_];
  __shared__ __align__(16) float p1s[16][H_];

  int t = threadIdx.x;
  int w = t >> 6, lane = t & 63;
  int bi = blockIdx.x;                      // global row
  int b = bi >> 9, i = bi & (N_-1);

  const uint4* ut8 = (const uint4*)((const unsigned short*)(ws + OFF_UT8))
                     + (size_t)b*8*N_;      // element [g][n]
  const uint4* us8 = (const uint4*)((const unsigned short*)(ws + OFF_US8))
                     + (size_t)b*64*A_;     // element [o][a]
  const uint4* xy4 = (const uint4*)((const unsigned*)(ws + OFF_XYP))
                     + (size_t)b*(N_/2)*(H_/4);  // element [k][h4]
  const float* wet = ws + OFF_WET;

  if (t < A_) {
    pkv[t] = ws[OFF_V + (size_t)(b*N_ + i)*A_ + t];
    pkw[t] = Wphi[t];
  }
  __syncthreads();

  // ---- Pass A: thread owns j = t; 8 x dwordx4 loads (8 a's each)
  float s = 0.f;
  {
    const float4* pv4 = (const float4*)pkv;
    const float4* pw4 = (const float4*)pkw;
    #pragma unroll
    for (int g = 0; g < 8; ++g) {
      uint4 d = ut8[(size_t)g*N_ + t];
      float4 v0 = pv4[2*g], v1 = pv4[2*g + 1];
      float4 w0 = pw4[2*g], w1 = pw4[2*g + 1];
      s = fmaf(w0.x, frcp(fmaf(v0.x, bf_lo(d.x), 1.f)), s);
      s = fmaf(w0.y, frcp(fmaf(v0.y, bf_hi(d.x), 1.f)), s);
      s = fmaf(w0.z, frcp(fmaf(v0.z, bf_lo(d.y), 1.f)), s);
      s = fmaf(w0.w, frcp(fmaf(v0.w, bf_hi(d.y), 1.f)), s);
      s = fmaf(w1.x, frcp(fmaf(v1.x, bf_lo(d.z), 1.f)), s);
      s = fmaf(w1.y, frcp(fmaf(v1.y, bf_hi(d.z), 1.f)), s);
      s = fmaf(w1.z, frcp(fmaf(v1.z, bf_lo(d.w), 1.f)), s);
      s = fmaf(w1.w, frcp(fmaf(v1.w, bf_hi(d.w), 1.f)), s);
    }
  }
  float p = fexp2(NEG2LE * s);              // shift-free softmax numerator
  sc[t] = p;
  float q = p;
  #pragma unroll
  for (int m = 1; m < 64; m <<= 1) q += __shfl_xor(q, m);
  if (lane == 0) reds[w] = q;
  __syncthreads();

  // ---- Pass C: lane = a; wave w covers j-octets o = oo*8 + w
  {
    float v = pkv[lane];
    const float4* sc4 = (const float4*)sc;
    float c = 0.f;
    #pragma unroll
    for (int oo = 0; oo < 8; ++oo) {
      int o = oo*8 + w;
      uint4 d = us8[(size_t)o*A_ + lane];
      float4 pA = sc4[o*2], pB = sc4[o*2 + 1];
      c = fmaf(pA.x, frcp(fmaf(v, bf_lo(d.x), 1.f)), c);
      c = fmaf(pA.y, frcp(fmaf(v, bf_hi(d.x), 1.f)), c);
      c = fmaf(pA.z, frcp(fmaf(v, bf_lo(d.y), 1.f)), c);
      c = fmaf(pA.w, frcp(fmaf(v, bf_hi(d.y), 1.f)), c);
      c = fmaf(pB.x, frcp(fmaf(v, bf_lo(d.z), 1.f)), c);
      c = fmaf(pB.y, frcp(fmaf(v, bf_hi(d.z), 1.f)), c);
      c = fmaf(pB.z, frcp(fmaf(v, bf_lo(d.w), 1.f)), c);
      c = fmaf(pB.w, frcp(fmaf(v, bf_hi(d.w), 1.f)), c);
    }
    ebw[w][lane] = c;
  }

  // ---- part1: thread = (qd = t>>5, h4 = t&31); 16 x dwordx4 (4 h-pairs)
  {
    int h4 = t & 31, qd = t >> 5;           // qd in [0,16): k = qd*16 + kc
    float d0 = 0.f, d1 = 0.f, d2 = 0.f, d3 = 0.f;
    #pragma unroll
    for (int kc = 0; kc < 16; ++kc) {
      int k = qd*16 + kc;
      uint4 d = xy4[(size_t)k*(H_/4) + h4];
      float pa = sc[2*k], pb = sc[2*k + 1];
      d0 = fmaf(pa, bf_lo(d.x), d0); d0 = fmaf(pb, bf_hi(d.x), d0);
      d1 = fmaf(pa, bf_lo(d.y), d1); d1 = fmaf(pb, bf_hi(d.y), d1);
      d2 = fmaf(pa, bf_lo(d.z), d2); d2 = fmaf(pb, bf_hi(d.z), d2);
      d3 = fmaf(pa, bf_lo(d.w), d3); d3 = fmaf(pb, bf_hi(d.w), d3);
    }
    *(float4*)&p1s[qd][h4*4] = make_float4(d0, d1, d2, d3);
  }
  __syncthreads();

  // ---- reduce ebar: ebar_un[a] = l - 2*sum_w ebw[w][a]
  if (t < A_) {
    float e = 0.f;
    #pragma unroll
    for (int k = 0; k < 8; ++k) e += ebw[k][t];
    float l = 0.f;
    #pragma unroll
    for (int k = 0; k < 8; ++k) l += reds[k];
    ebar[t] = l - 2.0f*e;
  }
  __syncthreads();

  // ---- epilogue: out = (part1_un + We^T·ebar_un)/l + be
  if (t < H_) {
    int h = t;
    float l = 0.f;
    #pragma unroll
    for (int k = 0; k < 8; ++k) l += reds[k];
    float acc = 0.f;
    #pragma unroll
    for (int k = 0; k < 16; ++k) acc += p1s[k][h];
    float e2 = 0.f;
    #pragma unroll 8
    for (int a = 0; a < A_; ++a) e2 = fmaf(ebar[a], wet[a*H_ + h], e2);
    out[(size_t)bi*H_ + h] = (acc + e2) * frcp(l) + be[h];
  }
}

extern "C" void kernel_launch(void* const* d_in, const int* in_sizes, int n_in,
                              void* d_out, int out_size, void* d_ws, size_t ws_size,
                              hipStream_t stream) {
  const float* X    = (const float*)d_in[0];
  const float* Wo   = (const float*)d_in[1];
  const float* W1   = (const float*)d_in[2];
  const float* Wphi = (const float*)d_in[3];
  const float* Wy   = (const float*)d_in[4];
  const float* by   = (const float*)d_in[5];
  const float* We   = (const float*)d_in[6];
  const float* be   = (const float*)d_in[7];
  float* out = (float*)d_out;
  float* ws  = (float*)d_ws;

  hipLaunchKernelGGL(prep_weights, dim3(64), dim3(256), 0, stream, Wo, W1, Wy, We, ws);
  hipLaunchKernelGGL(proj_kernel, dim3(B_*N_/2), dim3(256), 0, stream, X, by, ws);
  hipLaunchKernelGGL(attn_kernel, dim3(B_*N_), dim3(512), 0, stream, Wphi, be, ws, out);
}